// Round 15
// baseline (1677.857 us; speedup 1.0000x reference)
//
#include <hip/hip_runtime.h>

// ---------------- problem constants ----------------
#define Hd   256
#define Bd   16
#define Td   128
#define Ld   50
#define Vd   32000
#define G5H  1280     // 5*H

typedef __attribute__((ext_vector_type(8))) short short8v;  // 8 bf16 (4 VGPRs)
typedef __attribute__((ext_vector_type(4))) float f32x4;

__device__ __forceinline__ unsigned short f2bu(float f) {   // f32 -> bf16 bits (RNE)
  unsigned u = __float_as_uint(f);
  unsigned r = (u + 0x7fffu + ((u >> 16) & 1u)) >> 16;
  return (unsigned short)r;
}
__device__ __forceinline__ float bu2f(unsigned short b) {
  return __uint_as_float(((unsigned)b) << 16);
}
__device__ __forceinline__ float sigm(float x) { return 1.f / (1.f + __expf(-x)); }

// agent-scope (MALL) relaxed ops — proven cross-XCD path (rounds 2/7/10/13/14)
__device__ __forceinline__ void st_devu(unsigned* p, unsigned v) {
  __hip_atomic_store(p, v, __ATOMIC_RELAXED, __HIP_MEMORY_SCOPE_AGENT);
}
__device__ __forceinline__ unsigned ld_devu(const unsigned* p) {
  return __hip_atomic_load((unsigned*)p, __ATOMIC_RELAXED, __HIP_MEMORY_SCOPE_AGENT);
}
__device__ __forceinline__ void st_devd(double* p, double v) {
  __hip_atomic_store(p, v, __ATOMIC_RELAXED, __HIP_MEMORY_SCOPE_AGENT);
}
__device__ __forceinline__ double ld_devd(const double* p) {
  return __hip_atomic_load((double*)p, __ATOMIC_RELAXED, __HIP_MEMORY_SCOPE_AGENT);
}
__device__ __forceinline__ double pk2(float a, float b) {
  union { double d; float2 f; } u; u.f = make_float2(a, b); return u.d;
}

// ---------------- fp32 -> bf16 conversion + MFMA fragment packing ----------------
__global__ __launch_bounds__(256) void conv_kernel(
    const float* __restrict__ wv, const float* __restrict__ w_ih,
    const float* __restrict__ fcW, const float* __restrict__ w_hh,
    const float* __restrict__ Zm, const float* __restrict__ Pm,
    unsigned short* __restrict__ wv_b, unsigned short* __restrict__ wih_b,
    unsigned short* __restrict__ fcw_b, unsigned short* __restrict__ whh_f,
    unsigned short* __restrict__ z_f, unsigned short* __restrict__ p_f)
{
  const long N0 = 2048000, N1 = N0 + 81920, N2 = N1 + 2048000;
  const long NW = 81920, NZ = 16384, NP = 16384;         // frag float4-groups
  const long N5 = N2 + NW + NZ + NP;
  for (long idx = (long)blockIdx.x * blockDim.x + threadIdx.x; idx < N5;
       idx += (long)gridDim.x * blockDim.x) {
    if (idx < N2) {                                      // plain copies
      const float* src; unsigned short* dst; long off;
      if      (idx < N0) { src = wv;   dst = wv_b;  off = idx; }
      else if (idx < N1) { src = w_ih; dst = wih_b; off = idx - N0; }
      else               { src = fcW;  dst = fcw_b; off = idx - N1; }
      float4 v = *(const float4*)(src + off * 4);
      ushort4 o;
      o.x = f2bu(v.x); o.y = f2bu(v.y); o.z = f2bu(v.z); o.w = f2bu(v.w);
      *(ushort4*)(dst + off * 4) = o;
    } else {                                             // fragment packing
      long u = idx - N2;
      const float* src; unsigned short* dst;
      if      (u < NW)      { src = w_hh; dst = whh_f; }
      else if (u < NW + NZ) { src = Zm;   dst = z_f;  u -= NW; }
      else                  { src = Pm;   dst = p_f;  u -= NW + NZ; }
      long frag = u >> 7;                 // 128 float4-groups per 512-short frag
      int g128 = (int)(u & 127);
      int lane = g128 >> 1, e0 = (g128 & 1) * 4;
      long T = frag >> 3; int ks = (int)(frag & 7);
      int lr = lane & 15, lg = lane >> 4;
      float4 v = *(const float4*)(src + (T * 16 + lr) * 256 + ks * 32 + lg * 8 + e0);
      ushort4 o;
      o.x = f2bu(v.x); o.y = f2bu(v.y); o.z = f2bu(v.z); o.w = f2bu(v.w);
      *(ushort4*)(dst + u * 4) = o;
    }
  }
}

// ---------------- per-batch prep: goal embed, ht0, goal_term, E, sumE ----------------
__global__ __launch_bounds__(256) void prep_kernel(
    const int* __restrict__ g, const int* __restrict__ ingr,
    const float* __restrict__ wv, const float* __restrict__ Ug,
    const float* __restrict__ Ym, const float* __restrict__ yb,
    float* __restrict__ E_ws, float* __restrict__ sumE,
    float* __restrict__ goal_ws, float* __restrict__ HT0)
{
  __shared__ float ge[256];
  const int b = blockIdx.x, tid = threadIdx.x;
  float s = 0.f;
  for (int i = 0; i < 8; ++i) s += wv[((size_t)g[(b << 3) + i] << 8) + tid];
  ge[tid] = s;
  __syncthreads();
  float h0 = 0.f, gt = 0.f;
  const float* ur = Ug + (tid << 8);
  const float* yr = Ym + (tid << 8);
#pragma unroll 8
  for (int k = 0; k < Hd; k += 4) {
    float4 gv = *(const float4*)(ge + k);
    float4 uv = *(const float4*)(ur + k);
    float4 yv = *(const float4*)(yr + k);
    h0 = fmaf(gv.x, uv.x, h0); h0 = fmaf(gv.y, uv.y, h0);
    h0 = fmaf(gv.z, uv.z, h0); h0 = fmaf(gv.w, uv.w, h0);
    gt = fmaf(gv.x, yv.x, gt); gt = fmaf(gv.y, yv.y, gt);
    gt = fmaf(gv.z, yv.z, gt); gt = fmaf(gv.w, yv.w, gt);
  }
  HT0[(b << 8) + tid] = h0;                    // [b][c]
  goal_ws[(b << 8) + tid] = gt + yb[tid];      // [b][c]
  float se = 0.f;
  for (int l = 0; l < Ld; ++l) {
    float v = wv[((size_t)ingr[b * Ld + l] << 8) + tid];
    E_ws[((size_t)(b * Ld + l) << 8) + tid] = v;
    se += v;
  }
  sumE[(b << 8) + tid] = se;                   // [b][k]
}

// ---------------- bf16 MFMA GEMM (128x128 tile, K=256), two epilogues ----------------
template <int MODE>
__global__ __launch_bounds__(256) void gemm_bf16(
    const unsigned short* __restrict__ A, const unsigned short* __restrict__ Bmat,
    const int* __restrict__ ridx, const float* __restrict__ bias,
    float* __restrict__ C)
{
  __shared__ unsigned short As[128 * 64];
  __shared__ unsigned short Bs[128 * 64];
  const int tid = threadIdx.x;
  const int m0 = blockIdx.x << 7, n0 = blockIdx.y << 7;
  const int wave = tid >> 6, lane = tid & 63;
  const int wm = wave >> 1, wn = wave & 1;
  const int lr = lane & 15, lg = lane >> 4;

  f32x4 acc[4][4];
#pragma unroll
  for (int i = 0; i < 4; ++i)
#pragma unroll
    for (int jj = 0; jj < 4; ++jj) acc[i][jj] = (f32x4){0.f, 0.f, 0.f, 0.f};

  const int srow = tid >> 1, shalf = tid & 1;
  const unsigned short* arow;
  {
    int gm = m0 + srow;
    if (MODE == 0) {
      int tt = gm >> 4, bb = gm & 15;
      arow = A + (size_t)ridx[bb * Td + tt] * Hd;
    } else {
      arow = A + (size_t)gm * Hd;
    }
  }
  const unsigned short* brow = Bmat + (size_t)(n0 + srow) * Hd;

  for (int k0 = 0; k0 < Hd; k0 += 64) {
#pragma unroll
    for (int c = 0; c < 4; ++c) {
      int k = shalf * 32 + c * 8;
      uint4 va = *(const uint4*)(arow + k0 + k);
      uint4 vb = *(const uint4*)(brow + k0 + k);
      int byo = (srow << 7) + ((k << 1) ^ ((srow & 7) << 4));  // XOR swizzle
      *(uint4*)((char*)As + byo) = va;
      *(uint4*)((char*)Bs + byo) = vb;
    }
    __syncthreads();
#pragma unroll
    for (int kk = 0; kk < 2; ++kk) {
      short8v af[4], bfr[4];
      const int kb = kk * 32 + lg * 8;
#pragma unroll
      for (int i = 0; i < 4; ++i) {
        int ar = wm * 64 + i * 16 + lr;
        af[i] = *(const short8v*)((const char*)As + (ar << 7) + ((kb << 1) ^ ((ar & 7) << 4)));
        int br = wn * 64 + i * 16 + lr;
        bfr[i] = *(const short8v*)((const char*)Bs + (br << 7) + ((kb << 1) ^ ((br & 7) << 4)));
      }
#pragma unroll
      for (int i = 0; i < 4; ++i)
#pragma unroll
        for (int jj = 0; jj < 4; ++jj)
          acc[i][jj] = __builtin_amdgcn_mfma_f32_16x16x32_bf16(af[i], bfr[jj], acc[i][jj], 0, 0, 0);
    }
    __syncthreads();
  }
#pragma unroll
  for (int i = 0; i < 4; ++i)
#pragma unroll
    for (int jj = 0; jj < 4; ++jj) {
      int col = n0 + wn * 64 + jj * 16 + lr;
      float bv = bias[col];
#pragma unroll
      for (int r = 0; r < 4; ++r) {
        int row = m0 + wm * 64 + i * 16 + lg * 4 + r;
        float v = acc[i][jj][r] + bv;
        if (MODE == 0) {
          int tt = row >> 4, bb = row & 15;
          C[((size_t)(bb * Td + tt)) * G5H + col] = v;   // gi[b][t][grow]
        } else {
          C[(size_t)row * Vd + col] = v;
        }
      }
    }
}

// ---------------- recurrence v15: single-producer-wave publish, early flag ----------------
// Per iteration t: Ph0 [tp || poll+gather] -> Ph1 [gh(w0,2,3) || zd(w1) || E-dots(w4-7)]
// -> Ph2 [WAVE 0: gates+XH+S+A3+XP publish + wave-local drain + FLAG(t+2)  ||
//          alphas(w1-2)] -> Ph3 [F(w4-7)]. Flag fires a full phase early; drain is
// wave-local. Numerics identical to v14.
#define RNN_SMEM 150080
__global__ __launch_bounds__(512, 1) void rnn_kernel(
    const unsigned short* __restrict__ whh_f, const unsigned short* __restrict__ z_f,
    const unsigned short* __restrict__ p_f, const float* __restrict__ b_hh,
    const float* __restrict__ Sm, const float* __restrict__ z_bias,
    const float* __restrict__ gi, const float* __restrict__ goal_ws,
    const float* __restrict__ E_ws, const float* __restrict__ sumE,
    const float* __restrict__ HT0,
    unsigned short* __restrict__ out_all, float* __restrict__ d_out,
    double* __restrict__ XH, double* __restrict__ XP, unsigned* __restrict__ FL)
{
  extern __shared__ char smem[];
  unsigned short* w_lds = (unsigned short*)(smem);            // rows-slice, 10 tiles
  unsigned short* z_lds = (unsigned short*)(smem + 81920);    // 2 tiles
  unsigned short* p_lds = (unsigned short*)(smem + 98304);    // 16 tiles (ks=j)
  unsigned short* E_lds = (unsigned short*)(smem + 114688);   // 50 rows, 8x33 chunks
  float* hp    = (float*)(smem + 141088);   // 256
  float* gh_l  = (float*)(smem + 142112);   // 160
  float* zd    = (float*)(smem + 142752);   // 32
  float* se    = (float*)(smem + 142880);   // 256
  float* gl    = (float*)(smem + 143904);   // 32
  float* bh    = (float*)(smem + 144032);   // 160
  float* zb    = (float*)(smem + 144672);   // 32
  float* Sl    = (float*)(smem + 144800);   // 96 ([3][32])
  float* a_l   = (float*)(smem + 145184);   // 64
  float* d_l   = (float*)(smem + 145440);   // 64
  float* an_l  = (float*)(smem + 145696);   // 64
  float* au_l  = (float*)(smem + 145952);   // 64
  float* sd    = (float*)(smem + 146208);   // 4
  float* refl  = (float*)(smem + 146224);   // 4
  unsigned short* tp_hi = (unsigned short*)(smem + 146240);   // 256
  unsigned short* tp_lo = (unsigned short*)(smem + 146752);   // 256
  unsigned short* hs_hi = (unsigned short*)(smem + 147264);   // 32
  unsigned short* hs_lo = (unsigned short*)(smem + 147328);   // 32
  float* hrow  = (float*)(smem + 147392);   // 256 (ht(t) full)
  unsigned short* ht_hi = (unsigned short*)(smem + 148416);   // 256
  unsigned short* ht_lo = (unsigned short*)(smem + 148928);   // 256
  float* gi_l  = (float*)(smem + 149440);   // 5*32

  const int b  = blockIdx.x >> 3;
  const int j  = blockIdx.x & 7;
  const int hc0 = j << 5;
  const int tid = threadIdx.x;
  const int lane = tid & 63, wid = tid >> 6;
  const int lr = lane & 15, lg = lane >> 4;
  unsigned* FLb = FL + (b << 5);

  // ---- one-time staging ----
  for (int idx = tid; idx < 5120; idx += 512) {        // w_hh rows-slice
    int f = idx >> 6, e = idx & 63;
    int q = f >> 3, ks = f & 7;
    int T = (q >> 1) * 16 + 2 * j + (q & 1);
    *(uint4*)(w_lds + ((size_t)f << 9) + e * 8) =
        *(const uint4*)(whh_f + (((size_t)T * 8 + ks) << 9) + e * 8);
  }
  for (int idx = tid; idx < 1024; idx += 512) {        // Z rows-slice
    int f = idx >> 6, e = idx & 63;
    int T = 2 * j + (f >> 3), ks = f & 7;
    *(uint4*)(z_lds + ((size_t)f << 9) + e * 8) =
        *(const uint4*)(z_f + (((size_t)T * 8 + ks) << 9) + e * 8);
  }
  for (int idx = tid; idx < 1024; idx += 512) {        // P column-slice (ks=j)
    int f = idx >> 6, e = idx & 63;
    *(uint4*)(p_lds + ((size_t)f << 9) + e * 8) =
        *(const uint4*)(p_f + (((size_t)f * 8 + j) << 9) + e * 8);
  }
  for (int idx = tid; idx < Ld * 256; idx += 512) {    // E bf16, 33-short chunks
    int l = idx >> 8, k = idx & 255;
    E_lds[l * 264 + (k >> 5) * 33 + (k & 31)] =
        f2bu(E_ws[((size_t)(b * Ld + l) << 8) + k]);
  }
  if (tid < 160) bh[tid] = b_hh[((tid >> 5) << 8) + hc0 + (tid & 31)];
  if (tid < 96) Sl[tid] = Sm[((tid >> 5) << 8) + hc0 + (tid & 31)];
  if (tid < 32) {
    gl[tid] = goal_ws[(b << 8) + hc0 + tid];
    zb[tid] = z_bias[hc0 + tid];
  }
  if (tid < 256) {
    float s0 = sumE[(b << 8) + tid];
    se[tid] = s0;
    unsigned short hi = f2bu(s0);
    tp_hi[tid] = hi; tp_lo[tid] = f2bu(s0 - bu2f(hi));  // tp(0) = sumE
    float h0 = HT0[(b << 8) + tid];
    hrow[tid] = h0;
    unsigned short hh = f2bu(h0);
    ht_hi[tid] = hh; ht_lo[tid] = f2bu(h0 - bu2f(hh));
  }
  if (tid < 64) a_l[tid] = 0.f;
  __syncthreads();

  // ================= PROLOGUE: gh(0), zd(0), gates(0), publish, flag=1 =================
  if (wid < 4) {
#pragma unroll
    for (int i = 0; i < 3; ++i) {
      int q = wid + 4 * i;
      if (q < 10) {
        f32x4 acc = (f32x4){0.f, 0.f, 0.f, 0.f};
#pragma unroll
        for (int ks = 0; ks < 8; ++ks) {
          short8v av = *(const short8v*)(w_lds + ((size_t)(q * 8 + ks) << 9) + (lane << 3));
          short8v bv = (short8v){0,0,0,0,0,0,0,0};
          if (lr < 2)
            bv = *(const short8v*)((lr == 0 ? ht_hi : ht_lo) + ks * 32 + (lg << 3));
          acc = __builtin_amdgcn_mfma_f32_16x16x32_bf16(av, bv, acc, 0, 0, 0);
        }
#pragma unroll
        for (int r = 0; r < 4; ++r) {
          float v = acc[r] + __shfl_xor(acc[r], 1);
          if (lr == 0) gh_l[q * 16 + lg * 4 + r] = v;
        }
      }
    }
  } else if (wid == 4 || wid == 5) {
    int tz = wid - 4;
    f32x4 acc = (f32x4){0.f, 0.f, 0.f, 0.f};
#pragma unroll
    for (int ks = 0; ks < 8; ++ks) {
      short8v av = *(const short8v*)(z_lds + ((size_t)(tz * 8 + ks) << 9) + (lane << 3));
      short8v bv = (short8v){0,0,0,0,0,0,0,0};
      if (lr < 2)
        bv = *(const short8v*)((lr == 0 ? tp_hi : tp_lo) + ks * 32 + (lg << 3));
      acc = __builtin_amdgcn_mfma_f32_16x16x32_bf16(av, bv, acc, 0, 0, 0);
    }
#pragma unroll
    for (int r = 0; r < 4; ++r) {
      float v = acc[r] + __shfl_xor(acc[r], 1);
      if (lr == 0) zd[tz * 16 + lg * 4 + r] = v;
    }
  }
  __syncthreads();
  {
    double* XHp = XH + ((size_t)((0 * 16 + b) * 8 + j)) * 16;
    double* XPp = XP + ((size_t)((0 * 16 + b) * 8 + j)) * 132;
    if (tid < 32) {
      int cl = tid;
      const float* gib = gi + ((size_t)(b * Td)) * G5H + hc0 + cl;
      float g_ir = gib[0], g_iu = gib[256], g_in = gib[512];
      float g_ig = gib[768], g_ii = gib[1024];
      float hr = gh_l[cl]       + bh[cl];
      float hu = gh_l[32 + cl]  + bh[32 + cl];
      float hn = gh_l[64 + cl]  + bh[64 + cl];
      float hg = gh_l[96 + cl]  + bh[96 + cl];
      float hq = gh_l[128 + cl] + bh[128 + cl];
      float rt = sigm(g_ir + hr), zt = sigm(g_iu + hu);
      float st = sigm(g_ig + hg), qt = sigm(g_ii + hq);
      float htl = tanhf(g_in + rt * hn + st * gl[cl] + qt * (zd[cl] + zb[cl]));
      float h2 = htl + zt * (hrow[hc0 + cl] - htl);
      unsigned short hi = f2bu(h2);
      hs_hi[cl] = hi; hs_lo[cl] = f2bu(h2 - bu2f(hi));
      float h2o = __shfl_xor(h2, 1);
      if (!(cl & 1)) st_devd(XHp + (cl >> 1), pk2(h2, h2o));
      float p0 = Sl[cl] * h2, p1 = Sl[32 + cl] * h2, p2 = Sl[64 + cl] * h2;
      p0 += __shfl_xor(p0, 1);  p0 += __shfl_xor(p0, 2);  p0 += __shfl_xor(p0, 4);
      p0 += __shfl_xor(p0, 8);  p0 += __shfl_xor(p0, 16);
      p1 += __shfl_xor(p1, 1);  p1 += __shfl_xor(p1, 2);  p1 += __shfl_xor(p1, 4);
      p1 += __shfl_xor(p1, 8);  p1 += __shfl_xor(p1, 16);
      p2 += __shfl_xor(p2, 1);  p2 += __shfl_xor(p2, 2);  p2 += __shfl_xor(p2, 4);
      p2 += __shfl_xor(p2, 8);  p2 += __shfl_xor(p2, 16);
      if (cl == 0) {
        st_devd(XPp + 128, pk2(p0, p1));
        st_devd(XPp + 129, pk2(p2, 0.f));
      }
    }
    __syncthreads();
#pragma unroll
    for (int qq = 0; qq < 2; ++qq) {
      int q = wid * 2 + qq;
      short8v av = *(const short8v*)(p_lds + ((size_t)q << 9) + (lane << 3));
      short8v bv = (short8v){0,0,0,0,0,0,0,0};
      if (lr < 2)
        bv = *(const short8v*)((lr == 0 ? hs_hi : hs_lo) + (lg << 3));
      f32x4 acc = (f32x4){0.f, 0.f, 0.f, 0.f};
      acc = __builtin_amdgcn_mfma_f32_16x16x32_bf16(av, bv, acc, 0, 0, 0);
      float v0 = acc[0] + __shfl_xor(acc[0], 1);
      float v1 = acc[1] + __shfl_xor(acc[1], 1);
      float v2 = acc[2] + __shfl_xor(acc[2], 1);
      float v3 = acc[3] + __shfl_xor(acc[3], 1);
      if (lr == 0) {
        st_devd(XPp + q * 8 + lg * 2, pk2(v0, v1));
        st_devd(XPp + q * 8 + lg * 2 + 1, pk2(v2, v3));
      }
    }
    asm volatile("s_waitcnt vmcnt(0)" ::: "memory");
    __syncthreads();
    if (tid == 0) st_devu(FLb + j, 1u);
  }

  // ================= MAIN LOOP (4 barriers/step, early flag) =================
  for (int t = 0; t < Td; ++t) {
    const int par = t & 1, par1 = (t + 1) & 1;
    const double* XPr = XP + ((size_t)((par * 16 + b) * 8)) * 132;
    const double* XHr = XH + ((size_t)((par * 16 + b) * 8)) * 16;
    double* XPp = XP + ((size_t)((par1 * 16 + b) * 8 + j)) * 132;
    double* XHp = XH + ((size_t)((par1 * 16 + b) * 8 + j)) * 16;
    // ---- Ph0: tp(t+1) [waves 0-3]  ||  self-poll + gather [waves 4-7] ----
    if (tid < 256) {
      int k = tid;
      int kp = (k >> 5) * 33 + (k & 31);
      float acct = 0.f;
#pragma unroll 10
      for (int l = 0; l < Ld; ++l)
        acct = fmaf(a_l[l], bu2f(E_lds[l * 264 + kp]), acct);
      float tn = se[k] - acct;                   // tmp(t+1) = sum((1-a_t)*E)
      unsigned short th = f2bu(tn);
      tp_hi[k] = th; tp_lo[k] = f2bu(tn - bu2f(th));
    } else {
      unsigned tgt = (unsigned)(t + 1);
      int guard = 0;
      while (1) {
        unsigned v = (lane < 8) ? ld_devu(FLb + lane) : tgt;
        if (__all((int)(v >= tgt))) break;
        __builtin_amdgcn_s_sleep(1);
        if (++guard > (1 << 20)) break;
      }
      int u = tid - 256;
      if (u < 128) {                             // hp gather (waves 4-5)
        float2 f0, f1, f2, f3, f4, f5, f6, f7;
        { union { double d; float2 f; } u_;
          u_.d = ld_devd(XPr + 0 * 132 + u); f0 = u_.f;
          u_.d = ld_devd(XPr + 1 * 132 + u); f1 = u_.f;
          u_.d = ld_devd(XPr + 2 * 132 + u); f2 = u_.f;
          u_.d = ld_devd(XPr + 3 * 132 + u); f3 = u_.f;
          u_.d = ld_devd(XPr + 4 * 132 + u); f4 = u_.f;
          u_.d = ld_devd(XPr + 5 * 132 + u); f5 = u_.f;
          u_.d = ld_devd(XPr + 6 * 132 + u); f6 = u_.f;
          u_.d = ld_devd(XPr + 7 * 132 + u); f7 = u_.f; }
        hp[2 * u] =
          ((((((f0.x + f1.x) + f2.x) + f3.x) + f4.x) + f5.x) + f6.x) + f7.x;
        hp[2 * u + 1] =
          ((((((f0.y + f1.y) + f2.y) + f3.y) + f4.y) + f5.y) + f6.y) + f7.y;
      } else if (u < 192) {                      // ht gather (wave 6): 2 doubles
        int d0 = 2 * (u - 128);
#pragma unroll
        for (int s = 0; s < 2; ++s) {
          int d = d0 + s;
          union { double d; float2 f; } u_;
          u_.d = ld_devd(XHr + (d >> 4) * 16 + (d & 15));
          int c0 = (d >> 4) * 32 + 2 * (d & 15);
          float a0 = u_.f.x, a1 = u_.f.y;
          hrow[c0] = a0; hrow[c0 + 1] = a1;
          unsigned short h0 = f2bu(a0), h1 = f2bu(a1);
          ht_hi[c0] = h0;     ht_lo[c0] = f2bu(a0 - bu2f(h0));
          ht_hi[c0 + 1] = h1; ht_lo[c0 + 1] = f2bu(a1 - bu2f(h1));
          if (t == Td - 1 && j == 0) {
            d_out[(size_t)65536000 + (b << 8) + c0] = a0;
            d_out[(size_t)65536000 + (b << 8) + c0 + 1] = a1;
          }
        }
      } else {                                   // wave 7: sd gather + gi prefetch
        int u2 = u - 192;
        if (u2 < 3) {
          float2 f[8];
#pragma unroll
          for (int js = 0; js < 8; ++js) {
            union { double d; float2 f; } u_;
            u_.d = ld_devd(XPr + js * 132 + 128 + (u2 >> 1));
            f[js] = u_.f;
          }
          float sx, sy;
          sx = ((((((f[0].x + f[1].x) + f[2].x) + f[3].x) + f[4].x) + f[5].x)
                + f[6].x) + f[7].x;
          sy = ((((((f[0].y + f[1].y) + f[2].y) + f[3].y) + f[4].y) + f[5].y)
                + f[6].y) + f[7].y;
          if (u2 == 0) { sd[0] = sx; sd[1] = sy; }
          else if (u2 == 2) sd[2] = sx;
        } else if (u2 >= 8 && u2 < 40 && t < Td - 1) {
          int c = u2 - 8;
          const float* gib = gi + ((size_t)(b * Td + t + 1)) * G5H + hc0 + c;
          gi_l[c]       = gib[0];
          gi_l[32 + c]  = gib[256];
          gi_l[64 + c]  = gib[512];
          gi_l[96 + c]  = gib[768];
          gi_l[128 + c] = gib[1024];
        }
      }
    }
    __syncthreads();
    // ---- Ph1: gh(t+1) [waves 0,2,3: 4/3/3 tiles] || zd(t+1) [wave 1] || E-dots [w4-7] ----
    if (wid == 0 || wid == 2 || wid == 3) {
      int base0 = (wid == 0) ? 0 : (wid == 2 ? 4 : 7);
      int cnt   = (wid == 0) ? 4 : 3;
#pragma unroll 4
      for (int i = 0; i < 4; ++i) {
        if (i < cnt) {
          int q = base0 + i;
          f32x4 acc = (f32x4){0.f, 0.f, 0.f, 0.f};
#pragma unroll
          for (int ks = 0; ks < 8; ++ks) {
            short8v av = *(const short8v*)(w_lds + ((size_t)(q * 8 + ks) << 9) + (lane << 3));
            short8v bv = (short8v){0,0,0,0,0,0,0,0};
            if (lr < 2)
              bv = *(const short8v*)((lr == 0 ? ht_hi : ht_lo) + ks * 32 + (lg << 3));
            acc = __builtin_amdgcn_mfma_f32_16x16x32_bf16(av, bv, acc, 0, 0, 0);
          }
#pragma unroll
          for (int r = 0; r < 4; ++r) {
            float v = acc[r] + __shfl_xor(acc[r], 1);
            if (lr == 0) gh_l[q * 16 + lg * 4 + r] = v;
          }
        }
      }
    } else if (wid == 1) {
#pragma unroll
      for (int tz = 0; tz < 2; ++tz) {
        f32x4 acc = (f32x4){0.f, 0.f, 0.f, 0.f};
#pragma unroll
        for (int ks = 0; ks < 8; ++ks) {
          short8v av = *(const short8v*)(z_lds + ((size_t)(tz * 8 + ks) << 9) + (lane << 3));
          short8v bv = (short8v){0,0,0,0,0,0,0,0};
          if (lr < 2)
            bv = *(const short8v*)((lr == 0 ? tp_hi : tp_lo) + ks * 32 + (lg << 3));
          acc = __builtin_amdgcn_mfma_f32_16x16x32_bf16(av, bv, acc, 0, 0, 0);
        }
#pragma unroll
        for (int r = 0; r < 4; ++r) {
          float v = acc[r] + __shfl_xor(acc[r], 1);
          if (lr == 0) zd[tz * 16 + lg * 4 + r] = v;
        }
      }
    } else {
      int u = tid - 256;
      if (u < 200) {
        int l = u >> 2, q = u & 3;
        const unsigned short* er0 = E_lds + l * 264 + q * 66;
        const float* hq = hp + (q << 6);
        float p = 0.f;
#pragma unroll 8
        for (int i = 0; i < 16; ++i) {
          unsigned uu = *(const unsigned*)(er0 + 2 * i);
          float e0 = __uint_as_float(uu << 16);
          float e1 = __uint_as_float(uu & 0xffff0000u);
          p = fmaf(e0, hq[2 * i], p);
          p = fmaf(e1, hq[2 * i + 1], p);
        }
        const unsigned short* er1 = er0 + 33;
        const float* hq1 = hq + 32;
#pragma unroll 8
        for (int i = 0; i < 16; ++i) {
          unsigned uu = *(const unsigned*)(er1 + 2 * i);
          float e0 = __uint_as_float(uu << 16);
          float e1 = __uint_as_float(uu & 0xffff0000u);
          p = fmaf(e0, hq1[2 * i], p);
          p = fmaf(e1, hq1[2 * i + 1], p);
        }
        p += __shfl_xor(p, 1); p += __shfl_xor(p, 2);
        if (q == 0) d_l[l] = p;
      } else if (u == 204) {
        float s0 = 5.0f * sd[0], s1 = 5.0f * sd[1], s2 = 5.0f * sd[2];
        float m = fmaxf(s0, fmaxf(s1, s2));
        float e0 = __expf(s0 - m), e1 = __expf(s1 - m), e2 = __expf(s2 - m);
        float inv = 1.f / (e0 + e1 + e2);
        refl[0] = e0 * inv; refl[1] = e1 * inv; refl[2] = e2 * inv;
      }
    }
    __syncthreads();
    // ---- Ph2: WAVE 0 producer (gates+publish+A3+drain+FLAG) || alphas [w1-2] ----
    if (wid == 0) {
      if (t < Td - 1) {
        if (lane < 32) {
          int cl = lane;
          float hr = gh_l[cl]       + bh[cl];
          float hu = gh_l[32 + cl]  + bh[32 + cl];
          float hn = gh_l[64 + cl]  + bh[64 + cl];
          float hg = gh_l[96 + cl]  + bh[96 + cl];
          float hq = gh_l[128 + cl] + bh[128 + cl];
          float rt = sigm(gi_l[cl] + hr), zt = sigm(gi_l[32 + cl] + hu);
          float st = sigm(gi_l[96 + cl] + hg), qt = sigm(gi_l[128 + cl] + hq);
          float htl = tanhf(gi_l[64 + cl] + rt * hn + st * gl[cl] + qt * (zd[cl] + zb[cl]));
          float h2 = htl + zt * (hrow[hc0 + cl] - htl);
          unsigned short hi = f2bu(h2);
          hs_hi[cl] = hi; hs_lo[cl] = f2bu(h2 - bu2f(hi));
          float h2o = __shfl_xor(h2, 1);
          if (!(cl & 1)) st_devd(XHp + (cl >> 1), pk2(h2, h2o));
          float p0 = Sl[cl] * h2, p1 = Sl[32 + cl] * h2, p2 = Sl[64 + cl] * h2;
          p0 += __shfl_xor(p0, 1);  p0 += __shfl_xor(p0, 2);  p0 += __shfl_xor(p0, 4);
          p0 += __shfl_xor(p0, 8);  p0 += __shfl_xor(p0, 16);
          p1 += __shfl_xor(p1, 1);  p1 += __shfl_xor(p1, 2);  p1 += __shfl_xor(p1, 4);
          p1 += __shfl_xor(p1, 8);  p1 += __shfl_xor(p1, 16);
          p2 += __shfl_xor(p2, 1);  p2 += __shfl_xor(p2, 2);  p2 += __shfl_xor(p2, 4);
          p2 += __shfl_xor(p2, 8);  p2 += __shfl_xor(p2, 16);
          if (cl == 0) {
            st_devd(XPp + 128, pk2(p0, p1));
            st_devd(XPp + 129, pk2(p2, 0.f));
          }
        }
        // intra-wave fence: hs writes (lanes 0-31) -> A3 reads (all lanes)
        asm volatile("s_waitcnt lgkmcnt(0)" ::: "memory");
        __builtin_amdgcn_sched_barrier(0);
#pragma unroll
        for (int q = 0; q < 16; ++q) {           // A3: 16 hp-partial tiles (K=32)
          short8v av = *(const short8v*)(p_lds + ((size_t)q << 9) + (lane << 3));
          short8v bv = (short8v){0,0,0,0,0,0,0,0};
          if (lr < 2)
            bv = *(const short8v*)((lr == 0 ? hs_hi : hs_lo) + (lg << 3));
          f32x4 acc = (f32x4){0.f, 0.f, 0.f, 0.f};
          acc = __builtin_amdgcn_mfma_f32_16x16x32_bf16(av, bv, acc, 0, 0, 0);
          float v0 = acc[0] + __shfl_xor(acc[0], 1);
          float v1 = acc[1] + __shfl_xor(acc[1], 1);
          float v2 = acc[2] + __shfl_xor(acc[2], 1);
          float v3 = acc[3] + __shfl_xor(acc[3], 1);
          if (lr == 0) {
            st_devd(XPp + q * 8 + lg * 2, pk2(v0, v1));
            st_devd(XPp + q * 8 + lg * 2 + 1, pk2(v2, v3));
          }
        }
        asm volatile("s_waitcnt vmcnt(0)" ::: "memory");  // wave-local drain
        if (tid == 0) st_devu(FLb + j, (unsigned)(t + 2)); // EARLY FLAG
      }
    } else if (tid >= 64 && tid < 192) {         // alphas(t) [waves 1-2]
      int u = tid - 64;
      int which = u >> 6;
      int l = u & 63;
      float dv;
      if (which == 0) dv = (l < Ld) ? 2.0f * (1.f - a_l[l]) * d_l[l] : -3.4e38f;
      else            dv = (l < Ld) ? 2.0f * a_l[l] * d_l[l]         : -3.4e38f;
      float m = dv;
      m = fmaxf(m, __shfl_xor(m, 1));  m = fmaxf(m, __shfl_xor(m, 2));
      m = fmaxf(m, __shfl_xor(m, 4));  m = fmaxf(m, __shfl_xor(m, 8));
      m = fmaxf(m, __shfl_xor(m, 16)); m = fmaxf(m, __shfl_xor(m, 32));
      float e = (l < Ld) ? __expf(dv - m) : 0.f;
      float ss = e;
      ss += __shfl_xor(ss, 1);  ss += __shfl_xor(ss, 2);  ss += __shfl_xor(ss, 4);
      ss += __shfl_xor(ss, 8);  ss += __shfl_xor(ss, 16); ss += __shfl_xor(ss, 32);
      float al = e / ss;
      if (which == 0) an_l[l] = al; else au_l[l] = al;
    }
    __syncthreads();
    // ---- Ph3: F(t) + a-update [waves 4-7] ----
    if (tid >= 256) {
      int k = tid - 256;
      int kp = (k >> 5) * 33 + (k & 31);
      float accn = 0.f, accu = 0.f;
#pragma unroll 10
      for (int l = 0; l < Ld; ++l) {
        float e = bu2f(E_lds[l * 264 + kp]);
        accn = fmaf(an_l[l], e, accn);
        accu = fmaf(au_l[l], e, accu);
      }
      float outv = refl[0] * hp[k] + refl[1] * accn + refl[2] * accu;
      if ((t & 7) == j) {
        out_all[(((b << 7) + t) << 8) + k] = f2bu(outv);
        if (t == Td - 1) {
          for (int l = 0; l < Ld; ++l) {           // E_new = (1-a(126)done)*E
            size_t o = ((size_t)(b * Ld + l) << 8) + k;
            d_out[(size_t)65540896 + o] = (1.f - a_l[l]) * E_ws[o];
          }
        }
      }
      if (t < Td - 1 && k < Ld)
        a_l[k] = a_l[k] + refl[1] * an_l[k];
    }
    __syncthreads();
    if (t == Td - 1 && tid < Ld) {               // final a output
      float na = a_l[tid] + refl[1] * an_l[tid];
      if (j == 7) d_out[(size_t)65540096 + b * Ld + tid] = na;
    }
  }
}

// ---------------- host launcher ----------------
extern "C" void kernel_launch(void* const* d_in, const int* in_sizes, int n_in,
                              void* d_out, int out_size, void* d_ws, size_t ws_size,
                              hipStream_t stream)
{
  const int*   recipe = (const int*)d_in[0];
  const int*   g      = (const int*)d_in[1];
  const int*   ingr   = (const int*)d_in[2];
  const float* wv     = (const float*)d_in[3];
  const float* w_ih   = (const float*)d_in[4];
  const float* w_hh   = (const float*)d_in[5];
  const float* b_ih   = (const float*)d_in[6];
  const float* b_hh   = (const float*)d_in[7];
  const float* Z      = (const float*)d_in[8];
  const float* Y      = (const float*)d_in[9];
  const float* Ug     = (const float*)d_in[10];
  const float* z_bias = (const float*)d_in[11];
  const float* y_bias = (const float*)d_in[12];
  const float* S      = (const float*)d_in[13];
  const float* P      = (const float*)d_in[14];
  const float* fcW    = (const float*)d_in[15];
  const float* fcb    = (const float*)d_in[16];
  float* out = (float*)d_out;
  char* ws = (char*)d_ws;

  size_t off = 0;
  unsigned* FL             = (unsigned*)(ws + off);        off += 2048;
  double* XH               = (double*)(ws + off);          off += 32768;
  double* XP               = (double*)(ws + off);          off += 270336;
  unsigned short* wv_b     = (unsigned short*)(ws + off);  off += 16384000;
  unsigned short* wih_b    = (unsigned short*)(ws + off);  off += 655360;
  unsigned short* fcw_b    = (unsigned short*)(ws + off);  off += 16384000;
  unsigned short* whh_f    = (unsigned short*)(ws + off);  off += 655360;
  unsigned short* z_f      = (unsigned short*)(ws + off);  off += 131072;
  unsigned short* p_f      = (unsigned short*)(ws + off);  off += 131072;
  float* gi_ws             = (float*)(ws + off);           off += 10485760;
  float* E_ws              = (float*)(ws + off);           off += 819200;
  float* sumE              = (float*)(ws + off);           off += 16384;
  float* goal_ws           = (float*)(ws + off);           off += 16384;
  float* HT0               = (float*)(ws + off);           off += 16384;
  unsigned short* out_all  = (unsigned short*)(ws + off);  off += 1048576;

  hipMemsetAsync(FL, 0, 2048, stream);                 // replay-safe flags
  conv_kernel<<<4096, 256, 0, stream>>>(wv, w_ih, fcW, w_hh, Z, P,
                                        wv_b, wih_b, fcw_b, whh_f, z_f, p_f);
  prep_kernel<<<16, 256, 0, stream>>>(g, ingr, wv, Ug, Y, y_bias,
                                      E_ws, sumE, goal_ws, HT0);
  gemm_bf16<0><<<dim3(16, 10), 256, 0, stream>>>(wv_b, wih_b, recipe, b_ih, gi_ws);
  hipFuncSetAttribute((const void*)rnn_kernel,
                      hipFuncAttributeMaxDynamicSharedMemorySize, RNN_SMEM);
  rnn_kernel<<<128, 512, RNN_SMEM, stream>>>(whh_f, z_f, p_f, b_hh, S, z_bias,
                                             gi_ws, goal_ws, E_ws, sumE, HT0,
                                             out_all, out, XH, XP, FL);
  gemm_bf16<1><<<dim3(16, 250), 256, 0, stream>>>(out_all, fcw_b, nullptr, fcb, out);
}

// Round 16
// 1353.862 us; speedup vs baseline: 1.2393x; 1.2393x over previous
//
#include <hip/hip_runtime.h>

// ---------------- problem constants ----------------
#define Hd   256
#define Bd   16
#define Td   128
#define Ld   50
#define Vd   32000
#define G5H  1280     // 5*H

typedef __attribute__((ext_vector_type(8))) short short8v;  // 8 bf16 (4 VGPRs)
typedef __attribute__((ext_vector_type(4))) float f32x4;

__device__ __forceinline__ unsigned short f2bu(float f) {   // f32 -> bf16 bits (RNE)
  unsigned u = __float_as_uint(f);
  unsigned r = (u + 0x7fffu + ((u >> 16) & 1u)) >> 16;
  return (unsigned short)r;
}
__device__ __forceinline__ float bu2f(unsigned short b) {
  return __uint_as_float(((unsigned)b) << 16);
}
__device__ __forceinline__ float sigm(float x) { return 1.f / (1.f + __expf(-x)); }

// agent-scope (MALL) relaxed ops — proven cross-XCD path
__device__ __forceinline__ void st_devu(unsigned* p, unsigned v) {
  __hip_atomic_store(p, v, __ATOMIC_RELAXED, __HIP_MEMORY_SCOPE_AGENT);
}
__device__ __forceinline__ unsigned ld_devu(const unsigned* p) {
  return __hip_atomic_load((unsigned*)p, __ATOMIC_RELAXED, __HIP_MEMORY_SCOPE_AGENT);
}
__device__ __forceinline__ void st_devd(double* p, double v) {
  __hip_atomic_store(p, v, __ATOMIC_RELAXED, __HIP_MEMORY_SCOPE_AGENT);
}
__device__ __forceinline__ double ld_devd(const double* p) {
  return __hip_atomic_load((double*)p, __ATOMIC_RELAXED, __HIP_MEMORY_SCOPE_AGENT);
}
__device__ __forceinline__ double pk2(float a, float b) {
  union { double d; float2 f; } u; u.f = make_float2(a, b); return u.d;
}

// ---------------- fp32 -> bf16 conversion + MFMA fragment packing ----------------
__global__ __launch_bounds__(256) void conv_kernel(
    const float* __restrict__ wv, const float* __restrict__ w_ih,
    const float* __restrict__ fcW, const float* __restrict__ w_hh,
    const float* __restrict__ Zm, const float* __restrict__ Pm,
    unsigned short* __restrict__ wv_b, unsigned short* __restrict__ wih_b,
    unsigned short* __restrict__ fcw_b, unsigned short* __restrict__ whh_f,
    unsigned short* __restrict__ z_f, unsigned short* __restrict__ p_f)
{
  const long N0 = 2048000, N1 = N0 + 81920, N2 = N1 + 2048000;
  const long NW = 81920, NZ = 16384, NP = 16384;         // frag float4-groups
  const long N5 = N2 + NW + NZ + NP;
  for (long idx = (long)blockIdx.x * blockDim.x + threadIdx.x; idx < N5;
       idx += (long)gridDim.x * blockDim.x) {
    if (idx < N2) {                                      // plain copies
      const float* src; unsigned short* dst; long off;
      if      (idx < N0) { src = wv;   dst = wv_b;  off = idx; }
      else if (idx < N1) { src = w_ih; dst = wih_b; off = idx - N0; }
      else               { src = fcW;  dst = fcw_b; off = idx - N1; }
      float4 v = *(const float4*)(src + off * 4);
      ushort4 o;
      o.x = f2bu(v.x); o.y = f2bu(v.y); o.z = f2bu(v.z); o.w = f2bu(v.w);
      *(ushort4*)(dst + off * 4) = o;
    } else {                                             // fragment packing
      long u = idx - N2;
      const float* src; unsigned short* dst;
      if      (u < NW)      { src = w_hh; dst = whh_f; }
      else if (u < NW + NZ) { src = Zm;   dst = z_f;  u -= NW; }
      else                  { src = Pm;   dst = p_f;  u -= NW + NZ; }
      long frag = u >> 7;                 // 128 float4-groups per 512-short frag
      int g128 = (int)(u & 127);
      int lane = g128 >> 1, e0 = (g128 & 1) * 4;
      long T = frag >> 3; int ks = (int)(frag & 7);
      int lr = lane & 15, lg = lane >> 4;
      float4 v = *(const float4*)(src + (T * 16 + lr) * 256 + ks * 32 + lg * 8 + e0);
      ushort4 o;
      o.x = f2bu(v.x); o.y = f2bu(v.y); o.z = f2bu(v.z); o.w = f2bu(v.w);
      *(ushort4*)(dst + u * 4) = o;
    }
  }
}

// ---------------- per-batch prep: goal embed, ht0, goal_term, E, sumE ----------------
__global__ __launch_bounds__(256) void prep_kernel(
    const int* __restrict__ g, const int* __restrict__ ingr,
    const float* __restrict__ wv, const float* __restrict__ Ug,
    const float* __restrict__ Ym, const float* __restrict__ yb,
    float* __restrict__ E_ws, float* __restrict__ sumE,
    float* __restrict__ goal_ws, float* __restrict__ HT0)
{
  __shared__ float ge[256];
  const int b = blockIdx.x, tid = threadIdx.x;
  float s = 0.f;
  for (int i = 0; i < 8; ++i) s += wv[((size_t)g[(b << 3) + i] << 8) + tid];
  ge[tid] = s;
  __syncthreads();
  float h0 = 0.f, gt = 0.f;
  const float* ur = Ug + (tid << 8);
  const float* yr = Ym + (tid << 8);
#pragma unroll 8
  for (int k = 0; k < Hd; k += 4) {
    float4 gv = *(const float4*)(ge + k);
    float4 uv = *(const float4*)(ur + k);
    float4 yv = *(const float4*)(yr + k);
    h0 = fmaf(gv.x, uv.x, h0); h0 = fmaf(gv.y, uv.y, h0);
    h0 = fmaf(gv.z, uv.z, h0); h0 = fmaf(gv.w, uv.w, h0);
    gt = fmaf(gv.x, yv.x, gt); gt = fmaf(gv.y, yv.y, gt);
    gt = fmaf(gv.z, yv.z, gt); gt = fmaf(gv.w, yv.w, gt);
  }
  HT0[(b << 8) + tid] = h0;                    // [b][c]
  goal_ws[(b << 8) + tid] = gt + yb[tid];      // [b][c]
  float se = 0.f;
  for (int l = 0; l < Ld; ++l) {
    float v = wv[((size_t)ingr[b * Ld + l] << 8) + tid];
    E_ws[((size_t)(b * Ld + l) << 8) + tid] = v;
    se += v;
  }
  sumE[(b << 8) + tid] = se;                   // [b][k]
}

// ---------------- bf16 MFMA GEMM (128x128 tile, K=256), two epilogues ----------------
template <int MODE>
__global__ __launch_bounds__(256) void gemm_bf16(
    const unsigned short* __restrict__ A, const unsigned short* __restrict__ Bmat,
    const int* __restrict__ ridx, const float* __restrict__ bias,
    float* __restrict__ C)
{
  __shared__ unsigned short As[128 * 64];
  __shared__ unsigned short Bs[128 * 64];
  const int tid = threadIdx.x;
  const int m0 = blockIdx.x << 7, n0 = blockIdx.y << 7;
  const int wave = tid >> 6, lane = tid & 63;
  const int wm = wave >> 1, wn = wave & 1;
  const int lr = lane & 15, lg = lane >> 4;

  f32x4 acc[4][4];
#pragma unroll
  for (int i = 0; i < 4; ++i)
#pragma unroll
    for (int jj = 0; jj < 4; ++jj) acc[i][jj] = (f32x4){0.f, 0.f, 0.f, 0.f};

  const int srow = tid >> 1, shalf = tid & 1;
  const unsigned short* arow;
  {
    int gm = m0 + srow;
    if (MODE == 0) {
      int tt = gm >> 4, bb = gm & 15;
      arow = A + (size_t)ridx[bb * Td + tt] * Hd;
    } else {
      arow = A + (size_t)gm * Hd;
    }
  }
  const unsigned short* brow = Bmat + (size_t)(n0 + srow) * Hd;

  for (int k0 = 0; k0 < Hd; k0 += 64) {
#pragma unroll
    for (int c = 0; c < 4; ++c) {
      int k = shalf * 32 + c * 8;
      uint4 va = *(const uint4*)(arow + k0 + k);
      uint4 vb = *(const uint4*)(brow + k0 + k);
      int byo = (srow << 7) + ((k << 1) ^ ((srow & 7) << 4));  // XOR swizzle
      *(uint4*)((char*)As + byo) = va;
      *(uint4*)((char*)Bs + byo) = vb;
    }
    __syncthreads();
#pragma unroll
    for (int kk = 0; kk < 2; ++kk) {
      short8v af[4], bfr[4];
      const int kb = kk * 32 + lg * 8;
#pragma unroll
      for (int i = 0; i < 4; ++i) {
        int ar = wm * 64 + i * 16 + lr;
        af[i] = *(const short8v*)((const char*)As + (ar << 7) + ((kb << 1) ^ ((ar & 7) << 4)));
        int br = wn * 64 + i * 16 + lr;
        bfr[i] = *(const short8v*)((const char*)Bs + (br << 7) + ((kb << 1) ^ ((br & 7) << 4)));
      }
#pragma unroll
      for (int i = 0; i < 4; ++i)
#pragma unroll
        for (int jj = 0; jj < 4; ++jj)
          acc[i][jj] = __builtin_amdgcn_mfma_f32_16x16x32_bf16(af[i], bfr[jj], acc[i][jj], 0, 0, 0);
    }
    __syncthreads();
  }
#pragma unroll
  for (int i = 0; i < 4; ++i)
#pragma unroll
    for (int jj = 0; jj < 4; ++jj) {
      int col = n0 + wn * 64 + jj * 16 + lr;
      float bv = bias[col];
#pragma unroll
      for (int r = 0; r < 4; ++r) {
        int row = m0 + wm * 64 + i * 16 + lg * 4 + r;
        float v = acc[i][jj][r] + bv;
        if (MODE == 0) {
          int tt = row >> 4, bb = row & 15;
          C[((size_t)(bb * Td + tt)) * G5H + col] = v;   // gi[b][t][grow]
        } else {
          C[(size_t)row * Vd + col] = v;
        }
      }
    }
}

// ---------------- recurrence v16: v14 structure + per-wave early flags ----------------
// Identical to v14 except: waves 0-3 each fire their own flag (FLb[j*4+wid]) right
// after a wave-local vmcnt(0) drain in Ph3 — the flag no longer waits on F or the
// end-of-step barrier. Consumers poll 32 flags. Numerics identical to v14.
#define RNN_SMEM 150080
__global__ __launch_bounds__(512, 1) void rnn_kernel(
    const unsigned short* __restrict__ whh_f, const unsigned short* __restrict__ z_f,
    const unsigned short* __restrict__ p_f, const float* __restrict__ b_hh,
    const float* __restrict__ Sm, const float* __restrict__ z_bias,
    const float* __restrict__ gi, const float* __restrict__ goal_ws,
    const float* __restrict__ E_ws, const float* __restrict__ sumE,
    const float* __restrict__ HT0,
    unsigned short* __restrict__ out_all, float* __restrict__ d_out,
    double* __restrict__ XH, double* __restrict__ XP, unsigned* __restrict__ FL)
{
  extern __shared__ char smem[];
  unsigned short* w_lds = (unsigned short*)(smem);            // rows-slice, 10 tiles
  unsigned short* z_lds = (unsigned short*)(smem + 81920);    // 2 tiles
  unsigned short* p_lds = (unsigned short*)(smem + 98304);    // 16 tiles (ks=j)
  unsigned short* E_lds = (unsigned short*)(smem + 114688);   // 50 rows, 8x33 chunks
  float* hp    = (float*)(smem + 141088);   // 256
  float* gh_l  = (float*)(smem + 142112);   // 160
  float* zd    = (float*)(smem + 142752);   // 32
  float* se    = (float*)(smem + 142880);   // 256
  float* gl    = (float*)(smem + 143904);   // 32
  float* bh    = (float*)(smem + 144032);   // 160
  float* zb    = (float*)(smem + 144672);   // 32
  float* Sl    = (float*)(smem + 144800);   // 96 ([3][32])
  float* a_l   = (float*)(smem + 145184);   // 64
  float* d_l   = (float*)(smem + 145440);   // 64
  float* an_l  = (float*)(smem + 145696);   // 64
  float* au_l  = (float*)(smem + 145952);   // 64
  float* sd    = (float*)(smem + 146208);   // 4
  float* refl  = (float*)(smem + 146224);   // 4
  unsigned short* tp_hi = (unsigned short*)(smem + 146240);   // 256
  unsigned short* tp_lo = (unsigned short*)(smem + 146752);   // 256
  unsigned short* hs_hi = (unsigned short*)(smem + 147264);   // 32
  unsigned short* hs_lo = (unsigned short*)(smem + 147328);   // 32
  float* hrow  = (float*)(smem + 147392);   // 256 (ht(t) full)
  unsigned short* ht_hi = (unsigned short*)(smem + 148416);   // 256
  unsigned short* ht_lo = (unsigned short*)(smem + 148928);   // 256
  float* gi_l  = (float*)(smem + 149440);   // 5*32

  const int b  = blockIdx.x >> 3;
  const int j  = blockIdx.x & 7;
  const int hc0 = j << 5;
  const int tid = threadIdx.x;
  const int lane = tid & 63, wid = tid >> 6;
  const int lr = lane & 15, lg = lane >> 4;
  unsigned* FLb = FL + (b << 5);             // 32 flags: [j*4 + wave]

  // ---- one-time staging ----
  for (int idx = tid; idx < 5120; idx += 512) {        // w_hh rows-slice
    int f = idx >> 6, e = idx & 63;
    int q = f >> 3, ks = f & 7;
    int T = (q >> 1) * 16 + 2 * j + (q & 1);
    *(uint4*)(w_lds + ((size_t)f << 9) + e * 8) =
        *(const uint4*)(whh_f + (((size_t)T * 8 + ks) << 9) + e * 8);
  }
  for (int idx = tid; idx < 1024; idx += 512) {        // Z rows-slice
    int f = idx >> 6, e = idx & 63;
    int T = 2 * j + (f >> 3), ks = f & 7;
    *(uint4*)(z_lds + ((size_t)f << 9) + e * 8) =
        *(const uint4*)(z_f + (((size_t)T * 8 + ks) << 9) + e * 8);
  }
  for (int idx = tid; idx < 1024; idx += 512) {        // P column-slice (ks=j)
    int f = idx >> 6, e = idx & 63;
    *(uint4*)(p_lds + ((size_t)f << 9) + e * 8) =
        *(const uint4*)(p_f + (((size_t)f * 8 + j) << 9) + e * 8);
  }
  for (int idx = tid; idx < Ld * 256; idx += 512) {    // E bf16, 33-short chunks
    int l = idx >> 8, k = idx & 255;
    E_lds[l * 264 + (k >> 5) * 33 + (k & 31)] =
        f2bu(E_ws[((size_t)(b * Ld + l) << 8) + k]);
  }
  if (tid < 160) bh[tid] = b_hh[((tid >> 5) << 8) + hc0 + (tid & 31)];
  if (tid < 96) Sl[tid] = Sm[((tid >> 5) << 8) + hc0 + (tid & 31)];
  if (tid < 32) {
    gl[tid] = goal_ws[(b << 8) + hc0 + tid];
    zb[tid] = z_bias[hc0 + tid];
  }
  if (tid < 256) {
    float s0 = sumE[(b << 8) + tid];
    se[tid] = s0;
    unsigned short hi = f2bu(s0);
    tp_hi[tid] = hi; tp_lo[tid] = f2bu(s0 - bu2f(hi));  // tp(0) = sumE
    float h0 = HT0[(b << 8) + tid];
    hrow[tid] = h0;
    unsigned short hh = f2bu(h0);
    ht_hi[tid] = hh; ht_lo[tid] = f2bu(h0 - bu2f(hh));
  }
  if (tid < 64) a_l[tid] = 0.f;
  __syncthreads();

  // ================= PROLOGUE: gh(0), zd(0), gates(0), publish, flags=1 =================
  if (wid < 4) {
#pragma unroll
    for (int i = 0; i < 3; ++i) {
      int q = wid + 4 * i;
      if (q < 10) {
        f32x4 acc = (f32x4){0.f, 0.f, 0.f, 0.f};
#pragma unroll
        for (int ks = 0; ks < 8; ++ks) {
          short8v av = *(const short8v*)(w_lds + ((size_t)(q * 8 + ks) << 9) + (lane << 3));
          short8v bv = (short8v){0,0,0,0,0,0,0,0};
          if (lr < 2)
            bv = *(const short8v*)((lr == 0 ? ht_hi : ht_lo) + ks * 32 + (lg << 3));
          acc = __builtin_amdgcn_mfma_f32_16x16x32_bf16(av, bv, acc, 0, 0, 0);
        }
#pragma unroll
        for (int r = 0; r < 4; ++r) {
          float v = acc[r] + __shfl_xor(acc[r], 1);
          if (lr == 0) gh_l[q * 16 + lg * 4 + r] = v;
        }
      }
    }
  } else if (wid == 4 || wid == 5) {
    int tz = wid - 4;
    f32x4 acc = (f32x4){0.f, 0.f, 0.f, 0.f};
#pragma unroll
    for (int ks = 0; ks < 8; ++ks) {
      short8v av = *(const short8v*)(z_lds + ((size_t)(tz * 8 + ks) << 9) + (lane << 3));
      short8v bv = (short8v){0,0,0,0,0,0,0,0};
      if (lr < 2)
        bv = *(const short8v*)((lr == 0 ? tp_hi : tp_lo) + ks * 32 + (lg << 3));
      acc = __builtin_amdgcn_mfma_f32_16x16x32_bf16(av, bv, acc, 0, 0, 0);
    }
#pragma unroll
    for (int r = 0; r < 4; ++r) {
      float v = acc[r] + __shfl_xor(acc[r], 1);
      if (lr == 0) zd[tz * 16 + lg * 4 + r] = v;
    }
  }
  __syncthreads();
  {
    double* XHp = XH + ((size_t)((0 * 16 + b) * 8 + j)) * 16;
    double* XPp = XP + ((size_t)((0 * 16 + b) * 8 + j)) * 132;
    if (tid < 32) {
      int cl = tid;
      const float* gib = gi + ((size_t)(b * Td)) * G5H + hc0 + cl;
      float g_ir = gib[0], g_iu = gib[256], g_in = gib[512];
      float g_ig = gib[768], g_ii = gib[1024];
      float hr = gh_l[cl]       + bh[cl];
      float hu = gh_l[32 + cl]  + bh[32 + cl];
      float hn = gh_l[64 + cl]  + bh[64 + cl];
      float hg = gh_l[96 + cl]  + bh[96 + cl];
      float hq = gh_l[128 + cl] + bh[128 + cl];
      float rt = sigm(g_ir + hr), zt = sigm(g_iu + hu);
      float st = sigm(g_ig + hg), qt = sigm(g_ii + hq);
      float htl = tanhf(g_in + rt * hn + st * gl[cl] + qt * (zd[cl] + zb[cl]));
      float h2 = htl + zt * (hrow[hc0 + cl] - htl);
      unsigned short hi = f2bu(h2);
      hs_hi[cl] = hi; hs_lo[cl] = f2bu(h2 - bu2f(hi));
      float h2o = __shfl_xor(h2, 1);
      if (!(cl & 1)) st_devd(XHp + (cl >> 1), pk2(h2, h2o));
      float p0 = Sl[cl] * h2, p1 = Sl[32 + cl] * h2, p2 = Sl[64 + cl] * h2;
      p0 += __shfl_xor(p0, 1);  p0 += __shfl_xor(p0, 2);  p0 += __shfl_xor(p0, 4);
      p0 += __shfl_xor(p0, 8);  p0 += __shfl_xor(p0, 16);
      p1 += __shfl_xor(p1, 1);  p1 += __shfl_xor(p1, 2);  p1 += __shfl_xor(p1, 4);
      p1 += __shfl_xor(p1, 8);  p1 += __shfl_xor(p1, 16);
      p2 += __shfl_xor(p2, 1);  p2 += __shfl_xor(p2, 2);  p2 += __shfl_xor(p2, 4);
      p2 += __shfl_xor(p2, 8);  p2 += __shfl_xor(p2, 16);
      if (cl == 0) {
        st_devd(XPp + 128, pk2(p0, p1));
        st_devd(XPp + 129, pk2(p2, 0.f));
      }
    }
    __syncthreads();
#pragma unroll
    for (int qq = 0; qq < 2; ++qq) {
      int q = wid * 2 + qq;
      short8v av = *(const short8v*)(p_lds + ((size_t)q << 9) + (lane << 3));
      short8v bv = (short8v){0,0,0,0,0,0,0,0};
      if (lr < 2)
        bv = *(const short8v*)((lr == 0 ? hs_hi : hs_lo) + (lg << 3));
      f32x4 acc = (f32x4){0.f, 0.f, 0.f, 0.f};
      acc = __builtin_amdgcn_mfma_f32_16x16x32_bf16(av, bv, acc, 0, 0, 0);
      float v0 = acc[0] + __shfl_xor(acc[0], 1);
      float v1 = acc[1] + __shfl_xor(acc[1], 1);
      float v2 = acc[2] + __shfl_xor(acc[2], 1);
      float v3 = acc[3] + __shfl_xor(acc[3], 1);
      if (lr == 0) {
        st_devd(XPp + q * 8 + lg * 2, pk2(v0, v1));
        st_devd(XPp + q * 8 + lg * 2 + 1, pk2(v2, v3));
      }
    }
    asm volatile("s_waitcnt vmcnt(0)" ::: "memory");
    __syncthreads();
    if (tid < 4) st_devu(FLb + j * 4 + tid, 1u);
  }

  // ================= MAIN LOOP (4 barriers/step, per-wave early flags) =================
  for (int t = 0; t < Td; ++t) {
    const int par = t & 1, par1 = (t + 1) & 1;
    const double* XPr = XP + ((size_t)((par * 16 + b) * 8)) * 132;
    const double* XHr = XH + ((size_t)((par * 16 + b) * 8)) * 16;
    double* XPp = XP + ((size_t)((par1 * 16 + b) * 8 + j)) * 132;
    double* XHp = XH + ((size_t)((par1 * 16 + b) * 8 + j)) * 16;
    // ---- Ph0: tp(t+1) [waves 0-3]  ||  self-poll + gather [waves 4-7] ----
    if (tid < 256) {
      int k = tid;
      int kp = (k >> 5) * 33 + (k & 31);
      float acct = 0.f;
#pragma unroll 10
      for (int l = 0; l < Ld; ++l)
        acct = fmaf(a_l[l], bu2f(E_lds[l * 264 + kp]), acct);
      float tn = se[k] - acct;                   // tmp(t+1) = sum((1-a_t)*E)
      unsigned short th = f2bu(tn);
      tp_hi[k] = th; tp_lo[k] = f2bu(tn - bu2f(th));
    } else {
      unsigned tgt = (unsigned)(t + 1);
      int guard = 0;
      while (1) {
        unsigned v = (lane < 32) ? ld_devu(FLb + lane) : tgt;
        if (__all((int)(v >= tgt))) break;
        __builtin_amdgcn_s_sleep(1);
        if (++guard > (1 << 20)) break;
      }
      int u = tid - 256;
      if (u < 128) {                             // hp gather (waves 4-5)
        float2 f0, f1, f2, f3, f4, f5, f6, f7;
        { union { double d; float2 f; } u_;
          u_.d = ld_devd(XPr + 0 * 132 + u); f0 = u_.f;
          u_.d = ld_devd(XPr + 1 * 132 + u); f1 = u_.f;
          u_.d = ld_devd(XPr + 2 * 132 + u); f2 = u_.f;
          u_.d = ld_devd(XPr + 3 * 132 + u); f3 = u_.f;
          u_.d = ld_devd(XPr + 4 * 132 + u); f4 = u_.f;
          u_.d = ld_devd(XPr + 5 * 132 + u); f5 = u_.f;
          u_.d = ld_devd(XPr + 6 * 132 + u); f6 = u_.f;
          u_.d = ld_devd(XPr + 7 * 132 + u); f7 = u_.f; }
        hp[2 * u] =
          ((((((f0.x + f1.x) + f2.x) + f3.x) + f4.x) + f5.x) + f6.x) + f7.x;
        hp[2 * u + 1] =
          ((((((f0.y + f1.y) + f2.y) + f3.y) + f4.y) + f5.y) + f6.y) + f7.y;
      } else if (u < 192) {                      // ht gather (wave 6): 2 doubles
        int d0 = 2 * (u - 128);
#pragma unroll
        for (int s = 0; s < 2; ++s) {
          int d = d0 + s;
          union { double d; float2 f; } u_;
          u_.d = ld_devd(XHr + (d >> 4) * 16 + (d & 15));
          int c0 = (d >> 4) * 32 + 2 * (d & 15);
          float a0 = u_.f.x, a1 = u_.f.y;
          hrow[c0] = a0; hrow[c0 + 1] = a1;
          unsigned short h0 = f2bu(a0), h1 = f2bu(a1);
          ht_hi[c0] = h0;     ht_lo[c0] = f2bu(a0 - bu2f(h0));
          ht_hi[c0 + 1] = h1; ht_lo[c0 + 1] = f2bu(a1 - bu2f(h1));
          if (t == Td - 1 && j == 0) {
            d_out[(size_t)65536000 + (b << 8) + c0] = a0;
            d_out[(size_t)65536000 + (b << 8) + c0 + 1] = a1;
          }
        }
      } else {                                   // wave 7: sd gather + gi prefetch
        int u2 = u - 192;
        if (u2 < 3) {
          float2 f[8];
#pragma unroll
          for (int js = 0; js < 8; ++js) {
            union { double d; float2 f; } u_;
            u_.d = ld_devd(XPr + js * 132 + 128 + (u2 >> 1));
            f[js] = u_.f;
          }
          float sx, sy;
          sx = ((((((f[0].x + f[1].x) + f[2].x) + f[3].x) + f[4].x) + f[5].x)
                + f[6].x) + f[7].x;
          sy = ((((((f[0].y + f[1].y) + f[2].y) + f[3].y) + f[4].y) + f[5].y)
                + f[6].y) + f[7].y;
          if (u2 == 0) { sd[0] = sx; sd[1] = sy; }
          else if (u2 == 2) sd[2] = sx;
        } else if (u2 >= 8 && u2 < 40 && t < Td - 1) {
          int c = u2 - 8;
          const float* gib = gi + ((size_t)(b * Td + t + 1)) * G5H + hc0 + c;
          gi_l[c]       = gib[0];
          gi_l[32 + c]  = gib[256];
          gi_l[64 + c]  = gib[512];
          gi_l[96 + c]  = gib[768];
          gi_l[128 + c] = gib[1024];
        }
      }
    }
    __syncthreads();
    // ---- Ph1: zd(t+1) [waves 0-1] || gh(t+1) [waves 2-3] || E-dots+ref [waves 4-7] ----
    if (wid < 2) {
      int tz = wid;
      f32x4 acc = (f32x4){0.f, 0.f, 0.f, 0.f};
#pragma unroll
      for (int ks = 0; ks < 8; ++ks) {
        short8v av = *(const short8v*)(z_lds + ((size_t)(tz * 8 + ks) << 9) + (lane << 3));
        short8v bv = (short8v){0,0,0,0,0,0,0,0};
        if (lr < 2)
          bv = *(const short8v*)((lr == 0 ? tp_hi : tp_lo) + ks * 32 + (lg << 3));
        acc = __builtin_amdgcn_mfma_f32_16x16x32_bf16(av, bv, acc, 0, 0, 0);
      }
#pragma unroll
      for (int r = 0; r < 4; ++r) {
        float v = acc[r] + __shfl_xor(acc[r], 1);
        if (lr == 0) zd[tz * 16 + lg * 4 + r] = v;
      }
    } else if (wid < 4) {
#pragma unroll
      for (int i = 0; i < 5; ++i) {
        int q = (wid - 2) * 5 + i;
        f32x4 acc = (f32x4){0.f, 0.f, 0.f, 0.f};
#pragma unroll
        for (int ks = 0; ks < 8; ++ks) {
          short8v av = *(const short8v*)(w_lds + ((size_t)(q * 8 + ks) << 9) + (lane << 3));
          short8v bv = (short8v){0,0,0,0,0,0,0,0};
          if (lr < 2)
            bv = *(const short8v*)((lr == 0 ? ht_hi : ht_lo) + ks * 32 + (lg << 3));
          acc = __builtin_amdgcn_mfma_f32_16x16x32_bf16(av, bv, acc, 0, 0, 0);
        }
#pragma unroll
        for (int r = 0; r < 4; ++r) {
          float v = acc[r] + __shfl_xor(acc[r], 1);
          if (lr == 0) gh_l[q * 16 + lg * 4 + r] = v;
        }
      }
    } else {
      int u = tid - 256;
      if (u < 200) {
        int l = u >> 2, q = u & 3;
        const unsigned short* er0 = E_lds + l * 264 + q * 66;
        const float* hq = hp + (q << 6);
        float p = 0.f;
#pragma unroll 8
        for (int i = 0; i < 16; ++i) {
          unsigned uu = *(const unsigned*)(er0 + 2 * i);
          float e0 = __uint_as_float(uu << 16);
          float e1 = __uint_as_float(uu & 0xffff0000u);
          p = fmaf(e0, hq[2 * i], p);
          p = fmaf(e1, hq[2 * i + 1], p);
        }
        const unsigned short* er1 = er0 + 33;
        const float* hq1 = hq + 32;
#pragma unroll 8
        for (int i = 0; i < 16; ++i) {
          unsigned uu = *(const unsigned*)(er1 + 2 * i);
          float e0 = __uint_as_float(uu << 16);
          float e1 = __uint_as_float(uu & 0xffff0000u);
          p = fmaf(e0, hq1[2 * i], p);
          p = fmaf(e1, hq1[2 * i + 1], p);
        }
        p += __shfl_xor(p, 1); p += __shfl_xor(p, 2);
        if (q == 0) d_l[l] = p;
      } else if (u == 204) {
        float s0 = 5.0f * sd[0], s1 = 5.0f * sd[1], s2 = 5.0f * sd[2];
        float m = fmaxf(s0, fmaxf(s1, s2));
        float e0 = __expf(s0 - m), e1 = __expf(s1 - m), e2 = __expf(s2 - m);
        float inv = 1.f / (e0 + e1 + e2);
        refl[0] = e0 * inv; refl[1] = e1 * inv; refl[2] = e2 * inv;
      }
    }
    __syncthreads();
    // ---- Ph2: gates(t+1)+publish [wave 0] || alphas(t) [waves 1-2] ----
    if (tid < 32) {
      if (t < Td - 1) {
        int cl = tid;
        float hr = gh_l[cl]       + bh[cl];
        float hu = gh_l[32 + cl]  + bh[32 + cl];
        float hn = gh_l[64 + cl]  + bh[64 + cl];
        float hg = gh_l[96 + cl]  + bh[96 + cl];
        float hq = gh_l[128 + cl] + bh[128 + cl];
        float rt = sigm(gi_l[cl] + hr), zt = sigm(gi_l[32 + cl] + hu);
        float st = sigm(gi_l[96 + cl] + hg), qt = sigm(gi_l[128 + cl] + hq);
        float htl = tanhf(gi_l[64 + cl] + rt * hn + st * gl[cl] + qt * (zd[cl] + zb[cl]));
        float h2 = htl + zt * (hrow[hc0 + cl] - htl);
        unsigned short hi = f2bu(h2);
        hs_hi[cl] = hi; hs_lo[cl] = f2bu(h2 - bu2f(hi));
        float h2o = __shfl_xor(h2, 1);
        if (!(cl & 1)) st_devd(XHp + (cl >> 1), pk2(h2, h2o));
        float p0 = Sl[cl] * h2, p1 = Sl[32 + cl] * h2, p2 = Sl[64 + cl] * h2;
        p0 += __shfl_xor(p0, 1);  p0 += __shfl_xor(p0, 2);  p0 += __shfl_xor(p0, 4);
        p0 += __shfl_xor(p0, 8);  p0 += __shfl_xor(p0, 16);
        p1 += __shfl_xor(p1, 1);  p1 += __shfl_xor(p1, 2);  p1 += __shfl_xor(p1, 4);
        p1 += __shfl_xor(p1, 8);  p1 += __shfl_xor(p1, 16);
        p2 += __shfl_xor(p2, 1);  p2 += __shfl_xor(p2, 2);  p2 += __shfl_xor(p2, 4);
        p2 += __shfl_xor(p2, 8);  p2 += __shfl_xor(p2, 16);
        if (cl == 0) {
          st_devd(XPp + 128, pk2(p0, p1));
          st_devd(XPp + 129, pk2(p2, 0.f));
        }
      }
    } else if (tid >= 64 && tid < 192) {
      int u = tid - 64;
      int which = u >> 6;
      int l = u & 63;
      float dv;
      if (which == 0) dv = (l < Ld) ? 2.0f * (1.f - a_l[l]) * d_l[l] : -3.4e38f;
      else            dv = (l < Ld) ? 2.0f * a_l[l] * d_l[l]         : -3.4e38f;
      float m = dv;
      m = fmaxf(m, __shfl_xor(m, 1));  m = fmaxf(m, __shfl_xor(m, 2));
      m = fmaxf(m, __shfl_xor(m, 4));  m = fmaxf(m, __shfl_xor(m, 8));
      m = fmaxf(m, __shfl_xor(m, 16)); m = fmaxf(m, __shfl_xor(m, 32));
      float e = (l < Ld) ? __expf(dv - m) : 0.f;
      float ss = e;
      ss += __shfl_xor(ss, 1);  ss += __shfl_xor(ss, 2);  ss += __shfl_xor(ss, 4);
      ss += __shfl_xor(ss, 8);  ss += __shfl_xor(ss, 16); ss += __shfl_xor(ss, 32);
      float al = e / ss;
      if (which == 0) an_l[l] = al; else au_l[l] = al;
    }
    __syncthreads();
    // ---- Ph3: A3 publish + per-wave drain + FLAG [waves 0-3] || F(t)+a-upd [4-7] ----
    if (wid < 4) {
      if (t < Td - 1) {
#pragma unroll
        for (int qq = 0; qq < 4; ++qq) {
          int q = wid * 4 + qq;
          short8v av = *(const short8v*)(p_lds + ((size_t)q << 9) + (lane << 3));
          short8v bv = (short8v){0,0,0,0,0,0,0,0};
          if (lr < 2)
            bv = *(const short8v*)((lr == 0 ? hs_hi : hs_lo) + (lg << 3));
          f32x4 acc = (f32x4){0.f, 0.f, 0.f, 0.f};
          acc = __builtin_amdgcn_mfma_f32_16x16x32_bf16(av, bv, acc, 0, 0, 0);
          float v0 = acc[0] + __shfl_xor(acc[0], 1);
          float v1 = acc[1] + __shfl_xor(acc[1], 1);
          float v2 = acc[2] + __shfl_xor(acc[2], 1);
          float v3 = acc[3] + __shfl_xor(acc[3], 1);
          if (lr == 0) {
            st_devd(XPp + q * 8 + lg * 2, pk2(v0, v1));
            st_devd(XPp + q * 8 + lg * 2 + 1, pk2(v2, v3));
          }
        }
        asm volatile("s_waitcnt vmcnt(0)" ::: "memory");   // wave-local drain
        if (lane == 0)                                     // per-wave early flag
          st_devu(FLb + j * 4 + wid, (unsigned)(t + 2));
      }
    } else {
      int k = tid - 256;
      int kp = (k >> 5) * 33 + (k & 31);
      float accn = 0.f, accu = 0.f;
#pragma unroll 10
      for (int l = 0; l < Ld; ++l) {
        float e = bu2f(E_lds[l * 264 + kp]);
        accn = fmaf(an_l[l], e, accn);
        accu = fmaf(au_l[l], e, accu);
      }
      float outv = refl[0] * hp[k] + refl[1] * accn + refl[2] * accu;
      if ((t & 7) == j) {
        out_all[(((b << 7) + t) << 8) + k] = f2bu(outv);
        if (t == Td - 1) {
          for (int l = 0; l < Ld; ++l) {           // E_new = (1-a(t))*E
            size_t o = ((size_t)(b * Ld + l) << 8) + k;
            d_out[(size_t)65540896 + o] = (1.f - a_l[l]) * E_ws[o];
          }
        }
      }
      if (t < Td - 1 && k < Ld)
        a_l[k] = a_l[k] + refl[1] * an_l[k];
    }
    __syncthreads();
    if (t == Td - 1 && tid < Ld) {               // final a output
      float na = a_l[tid] + refl[1] * an_l[tid];
      if (j == 7) d_out[(size_t)65540096 + b * Ld + tid] = na;
    }
  }
}

// ---------------- host launcher ----------------
extern "C" void kernel_launch(void* const* d_in, const int* in_sizes, int n_in,
                              void* d_out, int out_size, void* d_ws, size_t ws_size,
                              hipStream_t stream)
{
  const int*   recipe = (const int*)d_in[0];
  const int*   g      = (const int*)d_in[1];
  const int*   ingr   = (const int*)d_in[2];
  const float* wv     = (const float*)d_in[3];
  const float* w_ih   = (const float*)d_in[4];
  const float* w_hh   = (const float*)d_in[5];
  const float* b_ih   = (const float*)d_in[6];
  const float* b_hh   = (const float*)d_in[7];
  const float* Z      = (const float*)d_in[8];
  const float* Y      = (const float*)d_in[9];
  const float* Ug     = (const float*)d_in[10];
  const float* z_bias = (const float*)d_in[11];
  const float* y_bias = (const float*)d_in[12];
  const float* S      = (const float*)d_in[13];
  const float* P      = (const float*)d_in[14];
  const float* fcW    = (const float*)d_in[15];
  const float* fcb    = (const float*)d_in[16];
  float* out = (float*)d_out;
  char* ws = (char*)d_ws;

  size_t off = 0;
  unsigned* FL             = (unsigned*)(ws + off);        off += 2048;
  double* XH               = (double*)(ws + off);          off += 32768;
  double* XP               = (double*)(ws + off);          off += 270336;
  unsigned short* wv_b     = (unsigned short*)(ws + off);  off += 16384000;
  unsigned short* wih_b    = (unsigned short*)(ws + off);  off += 655360;
  unsigned short* fcw_b    = (unsigned short*)(ws + off);  off += 16384000;
  unsigned short* whh_f    = (unsigned short*)(ws + off);  off += 655360;
  unsigned short* z_f      = (unsigned short*)(ws + off);  off += 131072;
  unsigned short* p_f      = (unsigned short*)(ws + off);  off += 131072;
  float* gi_ws             = (float*)(ws + off);           off += 10485760;
  float* E_ws              = (float*)(ws + off);           off += 819200;
  float* sumE              = (float*)(ws + off);           off += 16384;
  float* goal_ws           = (float*)(ws + off);           off += 16384;
  float* HT0               = (float*)(ws + off);           off += 16384;
  unsigned short* out_all  = (unsigned short*)(ws + off);  off += 1048576;

  hipMemsetAsync(FL, 0, 2048, stream);                 // replay-safe flags
  conv_kernel<<<4096, 256, 0, stream>>>(wv, w_ih, fcW, w_hh, Z, P,
                                        wv_b, wih_b, fcw_b, whh_f, z_f, p_f);
  prep_kernel<<<16, 256, 0, stream>>>(g, ingr, wv, Ug, Y, y_bias,
                                      E_ws, sumE, goal_ws, HT0);
  gemm_bf16<0><<<dim3(16, 10), 256, 0, stream>>>(wv_b, wih_b, recipe, b_ih, gi_ws);
  hipFuncSetAttribute((const void*)rnn_kernel,
                      hipFuncAttributeMaxDynamicSharedMemorySize, RNN_SMEM);
  rnn_kernel<<<128, 512, RNN_SMEM, stream>>>(whh_f, z_f, p_f, b_hh, S, z_bias,
                                             gi_ws, goal_ws, E_ws, sumE, HT0,
                                             out_all, out, XH, XP, FL);
  gemm_bf16<1><<<dim3(16, 250), 256, 0, stream>>>(out_all, fcw_b, nullptr, fcb, out);
}